// Round 1
// baseline (325.967 us; speedup 1.0000x reference)
//
#include <hip/hip_runtime.h>

// ConvAttention fused pipeline for MI355X (gfx950).
// Workspace requirement: ~57.1 MiB (q/k/vT/v_f32/O_hi/O_lo/out_w hi+lo/smalls).
//
// Pipeline:
//  kprep  : fold BN into pointwise weights; Wmix/beta for re-attention; out_w -> bf16 hi/lo
//  kqkv   : depthwise 3x3 + folded BN + 8x8 pointwise -> q,k (bf16), v (f32)
//  kvsum  : betaVsum[b,h,d] = beta[h] * sum_n v[b,h,n,d]   (fp32 exact rank-1 term)
//  kvtrans: v f32 [b,h,n,d] -> vT bf16 [b,h,d,n] (for PV B-fragments)
//  kattn  : two-pass flash attention w/ cross-head re-attention mix via LDS,
//           MFMA 16x16x32 bf16 for QK^T and PV, fp32 softmax stats
//  kout   : [8192,512]x[512,512]^T projection, bf16 MFMA with hi/lo 3-product split

#define EPS 1e-5f
#define SCALE 0.35355339059327373f  // H^-0.5, reference uses heads for scale

typedef float f32x4 __attribute__((ext_vector_type(4)));
typedef short short8 __attribute__((ext_vector_type(8)));

#define MFMA16(a, b, c) __builtin_amdgcn_mfma_f32_16x16x32_bf16(a, b, c, 0, 0, 0)

__device__ __forceinline__ unsigned short f2bf(float f) {
  union { float f; unsigned u; } v; v.f = f;
  return (unsigned short)((v.u + 0x7FFFu + ((v.u >> 16) & 1u)) >> 16);
}
__device__ __forceinline__ float bf2f(unsigned short h) {
  union { unsigned u; float f; } v; v.u = ((unsigned)h) << 16;
  return v.f;
}

// ---------------------------------------------------------------- kprep
__global__ __launch_bounds__(256) void kprep(
    const float* __restrict__ dwb, const float* __restrict__ bng,
    const float* __restrict__ bnb, const float* __restrict__ bnm,
    const float* __restrict__ bnv, const float* __restrict__ pww,
    const float* __restrict__ pwb, const float* __restrict__ rew,
    const float* __restrict__ reb, const float* __restrict__ vng,
    const float* __restrict__ vnb, const float* __restrict__ vnm,
    const float* __restrict__ vnv, const float* __restrict__ outw,
    float* __restrict__ smalls, unsigned short* __restrict__ wh,
    unsigned short* __restrict__ wl) {
  int g = blockIdx.x * 256 + threadIdx.x;
  if (g < 262144) {
    float v = outw[g];
    unsigned short hi = f2bf(v);
    wh[g] = hi;
    wl[g] = f2bf(v - bf2f(hi));
  }
  if (blockIdx.x == 0) {
    int t = threadIdx.x;
    if (t < 64) {  // Wmix[o][c] = re_w[o,c] * vn_g[o]/sqrt(vn_v[o]+eps)
      int o = t >> 3, c = t & 7;
      float s = vng[o] * rsqrtf(vnv[o] + EPS);
      smalls[t] = rew[o * 8 + c] * s;
    }
    if (t < 8) {   // beta[o]
      float s = vng[t] * rsqrtf(vnv[t] + EPS);
      smalls[64 + t] = (reb[t] - vnm[t]) * s + vnb[t];
    }
    if (t < 192) { // pw_eff[p][o][c] = pw_w * bn_scale[c]
      int p = t >> 6, rem = t & 63, o = rem >> 3, c = rem & 7;
      float s = bng[p * 8 + c] * rsqrtf(bnv[p * 8 + c] + EPS);
      smalls[72 + t] = pww[(p * 8 + o) * 8 + c] * s;
    }
    if (t < 24) {  // pwb_eff[p][o] = pw_b + sum_c pw_w*((dw_b-m)*s + b)
      int p = t / 8, o = t & 7;
      float acc = pwb[p * 8 + o];
      for (int c = 0; c < 8; ++c) {
        float s = bng[p * 8 + c] * rsqrtf(bnv[p * 8 + c] + EPS);
        acc += pww[(p * 8 + o) * 8 + c] *
               ((dwb[p * 8 + c] - bnm[p * 8 + c]) * s + bnb[p * 8 + c]);
      }
      smalls[264 + t] = acc;
    }
  }
}

// ---------------------------------------------------------------- kqkv
// thread = (b, n, d). Depthwise 3x3 over (n,d) per head (zero-pad at n and
// per-head d edges), then folded-BN pointwise 8x8 mix.
__global__ __launch_bounds__(256) void kqkv(
    const float* __restrict__ x, const float* __restrict__ dww,
    const float* __restrict__ smalls,
    unsigned short* __restrict__ qb, unsigned short* __restrict__ kb,
    float* __restrict__ vf) {
  int t = threadIdx.x;
  int blk = blockIdx.x;
  int b = blk >> 8;
  int n0 = (blk & 255) << 2;
  int d = t & 63;
  int n = n0 + (t >> 6);
  const float* pw_eff = smalls + 72;
  const float* pwb_eff = smalls + 264;
  float y[3][8];
  for (int h = 0; h < 8; ++h) {
    float nb[3][3];
#pragma unroll
    for (int ky = 0; ky < 3; ++ky) {
      int nn = n - 1 + ky;
      bool vr = (nn >= 0) && (nn < 1024);
      const float* xp = x + ((b * 1024 + nn) * 512 + h * 64 + d);
      nb[ky][0] = (vr && d > 0) ? xp[-1] : 0.f;
      nb[ky][1] = vr ? xp[0] : 0.f;
      nb[ky][2] = (vr && d < 63) ? xp[1] : 0.f;
    }
#pragma unroll
    for (int p = 0; p < 3; ++p) {
      const float* w = dww + (p * 8 + h) * 9;
      float a = 0.f;
#pragma unroll
      for (int ky = 0; ky < 3; ++ky)
#pragma unroll
        for (int kx = 0; kx < 3; ++kx) a += w[ky * 3 + kx] * nb[ky][kx];
      y[p][h] = a;
    }
  }
#pragma unroll
  for (int p = 0; p < 3; ++p) {
#pragma unroll
    for (int o = 0; o < 8; ++o) {
      float a = pwb_eff[p * 8 + o];
#pragma unroll
      for (int c = 0; c < 8; ++c) a += pw_eff[p * 64 + o * 8 + c] * y[p][c];
      int idx = ((b * 8 + o) * 1024 + n) * 64 + d;
      if (p == 0) qb[idx] = f2bf(a);
      else if (p == 1) kb[idx] = f2bf(a);
      else vf[idx] = a;
    }
  }
}

// ---------------------------------------------------------------- kvsum
__global__ __launch_bounds__(256) void kvsum(const float* __restrict__ vf,
                                             const float* __restrict__ smalls,
                                             float* __restrict__ bvs) {
  int t = blockIdx.x * 256 + threadIdx.x;  // 4096 = [b][h][d]
  int d = t & 63;
  int h = (t >> 6) & 7;
  int b = t >> 9;
  const float* vp = vf + ((b * 8 + h) * 1024) * 64 + d;
  float s = 0.f;
  for (int n = 0; n < 1024; ++n) s += vp[n * 64];
  bvs[t] = smalls[64 + h] * s;  // beta[h] * Vsum
}

// ---------------------------------------------------------------- kvtrans
__global__ __launch_bounds__(256) void kvtrans(const float* __restrict__ vf,
                                               unsigned short* __restrict__ vt) {
  __shared__ unsigned short lds[64 * 65];
  int bh = blockIdx.x >> 4;
  int nt = blockIdx.x & 15;
  int t = threadIdx.x;
  const float* src = vf + (bh * 1024 + nt * 64) * 64;
#pragma unroll
  for (int it = 0; it < 16; ++it) {
    int nn = (t >> 6) + it * 4;
    int d = t & 63;
    lds[nn * 65 + d] = f2bf(src[nn * 64 + d]);
  }
  __syncthreads();
  unsigned short* dst = vt + bh * 64 * 1024 + nt * 64;
#pragma unroll
  for (int it = 0; it < 16; ++it) {
    int d = (t >> 6) + it * 4;
    int n = t & 63;
    dst[d * 1024 + n] = lds[n * 65 + d];
  }
}

// ---------------------------------------------------------------- kattn
// Block = (b, 32-row i-tile), 8 waves = 8 heads. Two-pass flash:
//  P1: rowsum of exp(S) per head (no max needed; |S| small)
//  P2: recompute S, p = exp(S)/l, cross-head mix via swizzled LDS, PV MFMA.
__global__ __launch_bounds__(512, 2) void kattn(
    const unsigned short* __restrict__ qb, const unsigned short* __restrict__ kb,
    const unsigned short* __restrict__ vt, const float* __restrict__ smalls,
    unsigned short* __restrict__ ohi, unsigned short* __restrict__ olo) {
  __shared__ unsigned short plds[8 * 2048];  // [head][32 i][64 j] bf16, swizzled
  int b = blockIdx.x & 7;        // bid%8 -> XCD: all i-tiles of one b share an XCD L2
  int it = blockIdx.x >> 3;
  int i0 = it * 32;
  int h = threadIdx.x >> 6;
  int l = threadIdx.x & 63;
  int lrow = l & 15, lgrp = l >> 4;
  const unsigned short* qh = qb + (((b * 8 + h) * 1024) + i0) * 64;
  const unsigned short* kh = kb + ((b * 8 + h) * 1024) * 64;
  const unsigned short* vth = vt + ((b * 8 + h) * 64) * 1024;

  short8 Qf[2][2];
#pragma unroll
  for (int a = 0; a < 2; ++a)
#pragma unroll
    for (int kc = 0; kc < 2; ++kc)
      Qf[a][kc] = *(const short8*)(qh + (a * 16 + lrow) * 64 + kc * 32 + lgrp * 8);

  float Wr[8];
#pragma unroll
  for (int c = 0; c < 8; ++c) Wr[c] = smalls[h * 8 + c];

  // ---- phase 1: row sums of exp(S)
  float rs[2][4] = {};
  for (int jt = 0; jt < 16; ++jt) {
    short8 Kf[4][2];
#pragma unroll
    for (int q = 0; q < 4; ++q)
#pragma unroll
      for (int kc = 0; kc < 2; ++kc)
        Kf[q][kc] = *(const short8*)(kh + (jt * 64 + q * 16 + lrow) * 64 + kc * 32 + lgrp * 8);
    f32x4 acc[2][4] = {};
#pragma unroll
    for (int kc = 0; kc < 2; ++kc)
#pragma unroll
      for (int a = 0; a < 2; ++a)
#pragma unroll
        for (int q = 0; q < 4; ++q)
          acc[a][q] = MFMA16(Qf[a][kc], Kf[q][kc], acc[a][q]);
#pragma unroll
    for (int a = 0; a < 2; ++a)
#pragma unroll
      for (int q = 0; q < 4; ++q)
#pragma unroll
        for (int r = 0; r < 4; ++r) rs[a][r] += __expf(acc[a][q][r] * SCALE);
  }
#pragma unroll
  for (int a = 0; a < 2; ++a)
#pragma unroll
    for (int r = 0; r < 4; ++r) {
      float v = rs[a][r];
      v += __shfl_xor(v, 1);
      v += __shfl_xor(v, 2);
      v += __shfl_xor(v, 4);
      v += __shfl_xor(v, 8);
      rs[a][r] = 1.f / v;  // linv
    }

  // ---- phase 2
  f32x4 Oacc[2][4] = {};
  for (int jt = 0; jt < 16; ++jt) {
    short8 Kf[4][2];
#pragma unroll
    for (int q = 0; q < 4; ++q)
#pragma unroll
      for (int kc = 0; kc < 2; ++kc)
        Kf[q][kc] = *(const short8*)(kh + (jt * 64 + q * 16 + lrow) * 64 + kc * 32 + lgrp * 8);
    f32x4 acc[2][4] = {};
#pragma unroll
    for (int kc = 0; kc < 2; ++kc)
#pragma unroll
      for (int a = 0; a < 2; ++a)
#pragma unroll
        for (int q = 0; q < 4; ++q)
          acc[a][q] = MFMA16(Qf[a][kc], Kf[q][kc], acc[a][q]);
    // write normalized p to swizzled LDS (element swizzle: j ^ ((i>>2&3)<<4))
#pragma unroll
    for (int a = 0; a < 2; ++a)
#pragma unroll
      for (int r = 0; r < 4; ++r) {
        int i = a * 16 + lgrp * 4 + r;
        int swz = ((i >> 2) & 3) << 4;
        int base = h * 2048 + i * 64;
#pragma unroll
        for (int q = 0; q < 4; ++q) {
          float p = __expf(acc[a][q][r] * SCALE) * rs[a][r];
          plds[base + ((q * 16 + lrow) ^ swz)] = f2bf(p);
        }
      }
    __syncthreads();
    // mix heads -> PV A-fragments
    short8 PA[2][2];
#pragma unroll
    for (int a = 0; a < 2; ++a) {
      int irow = a * 16 + lrow;
      int swz = ((irow >> 2) & 3) << 4;
#pragma unroll
      for (int kc = 0; kc < 2; ++kc) {
        int eoff = irow * 64 + ((kc * 32 + lgrp * 8) ^ swz);
        float mixv[8] = {};
#pragma unroll
        for (int c = 0; c < 8; ++c) {
          short8 pv = *(const short8*)&plds[c * 2048 + eoff];
#pragma unroll
          for (int e = 0; e < 8; ++e)
            mixv[e] += Wr[c] * bf2f((unsigned short)pv[e]);
        }
        short8 af;
#pragma unroll
        for (int e = 0; e < 8; ++e) af[e] = (short)f2bf(mixv[e]);
        PA[a][kc] = af;
      }
    }
    // PV
#pragma unroll
    for (int nq = 0; nq < 4; ++nq)
#pragma unroll
      for (int kc = 0; kc < 2; ++kc) {
        short8 Vf = *(const short8*)(vth + (nq * 16 + lrow) * 1024 + jt * 64 + kc * 32 + lgrp * 8);
#pragma unroll
        for (int a = 0; a < 2; ++a) Oacc[a][nq] = MFMA16(PA[a][kc], Vf, Oacc[a][nq]);
      }
    __syncthreads();
  }
  // ---- epilogue: add exact rank-1 term, write O hi/lo bf16
  const float* bvs = smalls + 288;
#pragma unroll
  for (int a = 0; a < 2; ++a)
#pragma unroll
    for (int nq = 0; nq < 4; ++nq)
#pragma unroll
      for (int r = 0; r < 4; ++r) {
        int i = i0 + a * 16 + lgrp * 4 + r;
        int dd = nq * 16 + lrow;
        float o = Oacc[a][nq][r] + bvs[(b * 8 + h) * 64 + dd];
        int idx = ((b * 1024 + i) * 512) + h * 64 + dd;
        unsigned short hi = f2bf(o);
        ohi[idx] = hi;
        olo[idx] = f2bf(o - bf2f(hi));
      }
}

// ---------------------------------------------------------------- kout
// out[8192,512] = O[8192,512] @ out_w[512,512]^T + out_b, 3-product hi/lo split.
__global__ __launch_bounds__(256) void kout(
    const unsigned short* __restrict__ ohi, const unsigned short* __restrict__ olo,
    const unsigned short* __restrict__ wh, const unsigned short* __restrict__ wl,
    const float* __restrict__ outb, float* __restrict__ out) {
  int w = threadIdx.x >> 6, l = threadIdx.x & 63;
  int lrow = l & 15, lgrp = l >> 4;
  int i0 = blockIdx.x * 128 + w * 32;
  int n0 = blockIdx.y * 64;
  f32x4 acc[2][4] = {};
  for (int kc = 0; kc < 16; ++kc) {
    short8 Ah[2], Al[2], Bh[4], Bl[4];
#pragma unroll
    for (int a = 0; a < 2; ++a) {
      int ro = (i0 + a * 16 + lrow) * 512 + kc * 32 + lgrp * 8;
      Ah[a] = *(const short8*)(ohi + ro);
      Al[a] = *(const short8*)(olo + ro);
    }
#pragma unroll
    for (int nq = 0; nq < 4; ++nq) {
      int ro = (n0 + nq * 16 + lrow) * 512 + kc * 32 + lgrp * 8;
      Bh[nq] = *(const short8*)(wh + ro);
      Bl[nq] = *(const short8*)(wl + ro);
    }
#pragma unroll
    for (int a = 0; a < 2; ++a)
#pragma unroll
      for (int nq = 0; nq < 4; ++nq) {
        acc[a][nq] = MFMA16(Ah[a], Bh[nq], acc[a][nq]);
        acc[a][nq] = MFMA16(Ah[a], Bl[nq], acc[a][nq]);
        acc[a][nq] = MFMA16(Al[a], Bh[nq], acc[a][nq]);
      }
  }
#pragma unroll
  for (int a = 0; a < 2; ++a)
#pragma unroll
    for (int nq = 0; nq < 4; ++nq)
#pragma unroll
      for (int r = 0; r < 4; ++r) {
        int row = i0 + a * 16 + lgrp * 4 + r;
        int n = n0 + nq * 16 + lrow;
        out[row * 512 + n] = acc[a][nq][r] + outb[n];
      }
}

// ---------------------------------------------------------------- launch
extern "C" void kernel_launch(void* const* d_in, const int* in_sizes, int n_in,
                              void* d_out, int out_size, void* d_ws, size_t ws_size,
                              hipStream_t stream) {
  const float* x   = (const float*)d_in[0];
  const float* dww = (const float*)d_in[1];
  const float* dwb = (const float*)d_in[2];
  const float* bng = (const float*)d_in[3];
  const float* bnb = (const float*)d_in[4];
  const float* bnm = (const float*)d_in[5];
  const float* bnv = (const float*)d_in[6];
  const float* pww = (const float*)d_in[7];
  const float* pwb = (const float*)d_in[8];
  const float* rew = (const float*)d_in[9];
  const float* reb = (const float*)d_in[10];
  const float* vng = (const float*)d_in[11];
  const float* vnb = (const float*)d_in[12];
  const float* vnm = (const float*)d_in[13];
  const float* vnv = (const float*)d_in[14];
  const float* outw = (const float*)d_in[15];
  const float* outb = (const float*)d_in[16];

  char* ws = (char*)d_ws;
  const size_t MB = 1024 * 1024;
  unsigned short* qb  = (unsigned short*)(ws);
  unsigned short* kb  = (unsigned short*)(ws + 8 * MB);
  unsigned short* vt  = (unsigned short*)(ws + 16 * MB);
  float*          vf  = (float*)(ws + 24 * MB);
  unsigned short* ohi = (unsigned short*)(ws + 40 * MB);
  unsigned short* olo = (unsigned short*)(ws + 48 * MB);
  unsigned short* wh  = (unsigned short*)(ws + 56 * MB);
  unsigned short* wl  = (unsigned short*)(ws + 56 * MB + 512 * 1024);
  float*       smalls = (float*)(ws + 57 * MB);

  hipLaunchKernelGGL(kprep, dim3(1024), dim3(256), 0, stream,
                     dwb, bng, bnb, bnm, bnv, pww, pwb, rew, reb, vng, vnb,
                     vnm, vnv, outw, smalls, wh, wl);
  hipLaunchKernelGGL(kqkv, dim3(2048), dim3(256), 0, stream,
                     x, dww, smalls, qb, kb, vf);
  hipLaunchKernelGGL(kvsum, dim3(16), dim3(256), 0, stream, vf, smalls, smalls + 288);
  hipLaunchKernelGGL(kvtrans, dim3(1024), dim3(256), 0, stream, vf, vt);
  hipLaunchKernelGGL(kattn, dim3(256), dim3(512), 0, stream,
                     qb, kb, vt, smalls, ohi, olo);
  hipLaunchKernelGGL(kout, dim3(64, 8), dim3(256), 0, stream,
                     ohi, olo, wh, wl, outb, (float*)d_out);
}